// Round 13
// baseline (165.773 us; speedup 1.0000x reference)
//
#include <hip/hip_runtime.h>
#include <math.h>

#define D 8
// ---- coarse-sort fast path ----
#define NPC 512            // nodes per coarse bucket (power of 2)
#define NPCSH 9
#define NCMAX 512          // max coarse buckets on fast path
#define EPB 3072           // edges per sort-kernel block
#define APT 1024           // sort-kernel threads
#define BCH 1536           // phase-B chunk (records)
#define BPT 1024           // phase-B threads
#define UE 4               // K1: edges-unroll per thread-pair
// ---- pairs fallback path ----
#define BSH 6
#define BMASK 63
#define NBMAX 1600
#define EPBF 6250          // fallback pairs-path edges per block
#define RPT5 512

typedef __attribute__((ext_vector_type(4))) float f4v;

// ---- bf16 helpers ----
__device__ __forceinline__ unsigned pk_bf16(float a, float b) {
    unsigned ua = __float_as_uint(a), ub = __float_as_uint(b);
    ua = (ua + 0x7FFFu + ((ua >> 16) & 1u)) >> 16;   // RTNE
    ub = (ub + 0x7FFFu + ((ub >> 16) & 1u)) >> 16;
    return ua | (ub << 16);
}
__device__ __forceinline__ float bf_lo(unsigned u) { return __uint_as_float(u << 16); }
__device__ __forceinline__ float bf_hi(unsigned u) { return __uint_as_float(u & 0xFFFF0000u); }

__global__ void zero_cursors_kernel(unsigned* __restrict__ cur, int n) {
    int i = blockIdx.x * blockDim.x + threadIdx.x;
    if (i < n) cur[i] = 0u;
}

// block-wide exclusive scan over NB bins (NB multiple of 64, <= blockDim)
template<int NB>
__device__ __forceinline__ void scan_bins(unsigned* hist, unsigned* incl,
                                          unsigned* starts, unsigned* cur,
                                          unsigned* wsum, unsigned* woff) {
    int tid = threadIdx.x;
    if (tid < NB) {
        int l = tid & 63;
        unsigned v = hist[tid], s = v;
#pragma unroll
        for (int dd = 1; dd < 64; dd <<= 1) {
            unsigned tt = __shfl_up(s, dd, 64);
            if (l >= dd) s += tt;
        }
        incl[tid] = s;
        if (l == 63) wsum[tid >> 6] = s;
    }
    __syncthreads();
    if (tid == 0) {
        unsigned o = 0;
#pragma unroll
        for (int w = 0; w < NB / 64; ++w) { woff[w] = o; o += wsum[w]; }
    }
    __syncthreads();
    if (tid < NB) {
        unsigned st = incl[tid] - hist[tid] + woff[tid >> 6];
        starts[tid] = st;
        cur[tid] = st;
    }
    __syncthreads();
}

// =============== K1: gather/compute, 2 lanes/edge, 4-edge unroll ===============

__global__ __launch_bounds__(256, 6) void edge_compute4_kernel(
    const float4* __restrict__ x4,
    const int* __restrict__ src_idx,
    const int* __restrict__ dst_idx,
    const float4* __restrict__ ea4,
    float4* __restrict__ out_edge4,
    int n_edges)
{
    const int h    = threadIdx.x & 1;          // low/high float4 half
    const int eo   = threadIdx.x >> 1;         // 0..127
    const int base = blockIdx.x * (128 * UE);

    int e[UE], s[UE], t[UE];
    bool v[UE];
#pragma unroll
    for (int u = 0; u < UE; ++u) {
        e[u] = base + u * 128 + eo;
        v[u] = e[u] < n_edges;
        s[u] = v[u] ? src_idx[e[u]] : 0;
        t[u] = v[u] ? dst_idx[e[u]] : 0;
    }

    // batch all gathers + streaming loads before any compute (max MLP)
    float4 xs[UE], xd[UE], a[UE];
#pragma unroll
    for (int u = 0; u < UE; ++u) {
        if (v[u]) {
            xs[u] = x4[(size_t)s[u] * 2 + h];   // adjacent lanes merge to 1 line
            xd[u] = x4[(size_t)t[u] * 2 + h];
        }
    }
#pragma unroll
    for (int u = 0; u < UE; ++u) {
        if (v[u]) {
            f4v av = __builtin_nontemporal_load(
                (const f4v*)&ea4[(size_t)e[u] * 2 + h]);
            a[u] = *(float4*)&av;
        }
    }

#pragma unroll
    for (int u = 0; u < UE; ++u) {
        if (v[u]) {
            f4v d;
            d.x = (xd[u].x - xs[u].x) / a[u].x;
            d.y = (xd[u].y - xs[u].y) / a[u].y;
            d.z = (xd[u].z - xs[u].z) / a[u].z;
            d.w = (xd[u].w - xs[u].w) / a[u].w;
            __builtin_nontemporal_store(d, (f4v*)&out_edge4[(size_t)e[u] * 2 + h]);
        }
    }
}

// =============== K2: streaming counting-sort into coarse regions ===============

__global__ __launch_bounds__(APT) void edge_sortk_kernel(
    const int* __restrict__ dst_idx,
    const float4* __restrict__ edge4,
    unsigned* __restrict__ gcur,          // [nc]
    uint4* __restrict__ vals,             // [nc*cap]
    unsigned short* __restrict__ locs,    // [nc*cap]
    int n_edges, int nc, int cap)
{
    __shared__ uint4 pay[EPB];            // 49152 B — bf16 payload (sorted order)
    __shared__ unsigned meta[EPB];        // 12288 B — node id (sorted order)
    __shared__ unsigned hist[NCMAX];
    __shared__ unsigned incl[NCMAX];
    __shared__ unsigned starts[NCMAX];
    __shared__ unsigned cur[NCMAX];
    __shared__ unsigned base[NCMAX];
    __shared__ unsigned wsum[NCMAX / 64], woff[NCMAX / 64];

    for (int c = threadIdx.x; c < NCMAX; c += APT) hist[c] = 0u;
    __syncthreads();

    const int start = blockIdx.x * EPB;
    int lim = n_edges - start;
    if (lim > EPB) lim = EPB;
    if (lim < 0) lim = 0;

    // pass A: histogram of coarse buckets (dst streaming read)
    for (int i = threadIdx.x; i < lim; i += APT) {
        unsigned t = (unsigned)dst_idx[start + i];
        atomicAdd(&hist[t >> NPCSH], 1u);
    }
    __syncthreads();

    scan_bins<NCMAX>(hist, incl, starts, cur, wsum, woff);

    // reserve global run space
    if (threadIdx.x < (unsigned)nc)
        base[threadIdx.x] = hist[threadIdx.x]
            ? atomicAdd(&gcur[threadIdx.x], hist[threadIdx.x]) : 0u;

    // pass B: stream edge_deriv (coalesced), convert bf16, direct-scatter into
    // sorted LDS position
    for (int i = threadIdx.x; i < lim; i += APT) {
        int e = start + i;
        unsigned t = (unsigned)dst_idx[e];      // L2-hot re-read
        float4 d0 = edge4[(size_t)e * 2 + 0];
        float4 d1 = edge4[(size_t)e * 2 + 1];
        unsigned p = atomicAdd(&cur[t >> NPCSH], 1u);
        uint4 v = { pk_bf16(d0.x, d0.y), pk_bf16(d0.z, d0.w),
                    pk_bf16(d1.x, d1.y), pk_bf16(d1.z, d1.w) };
        pay[p] = v;
        meta[p] = t;
    }
    __syncthreads();

    // pass C: coalesced LDS read -> coalesced global run write
    for (int p = threadIdx.x; p < lim; p += APT) {
        unsigned t = meta[p];
        unsigned c = t >> NPCSH;
        unsigned addr = base[c] + ((unsigned)p - starts[c]);
        if (addr < (unsigned)cap) {
            size_t gi = (size_t)c * cap + addr;
            vals[gi] = pay[p];
            locs[gi] = (unsigned short)(t & (NPC - 1));
        }
    }
}

// =============== K3: coarse reduce (round-8, proven ~7 µs) ===============

__global__ __launch_bounds__(BPT) void coarse_reduce_kernel(
    const unsigned* __restrict__ gcur,
    const uint4* __restrict__ vals,
    const unsigned short* __restrict__ locs,
    float4* __restrict__ out_node4,
    int n_nodes, int cap)
{
    __shared__ float acc[NPC * 9];        // 18432 B
    __shared__ uint4 vstage[BCH];         // 24576 B
    __shared__ unsigned hist[NPC];
    __shared__ unsigned incl[NPC];
    __shared__ unsigned starts[NPC];
    __shared__ unsigned cur[NPC];
    __shared__ unsigned wsum[NPC / 64], woff[NPC / 64];

    const int c = blockIdx.x;
    int count = (int)gcur[c];
    if (count > cap) count = cap;
    const uint4* vsrc = vals + (size_t)c * cap;
    const unsigned short* lsrc = locs + (size_t)c * cap;

    for (int j = threadIdx.x; j < NPC * 9; j += BPT) acc[j] = 0.0f;
    __syncthreads();

    for (int cb = 0; cb < count; cb += BCH) {
        int cnt = count - cb;
        if (cnt > BCH) cnt = BCH;

        for (int j = threadIdx.x; j < NPC; j += BPT) hist[j] = 0u;
        __syncthreads();

        uint4 r0, r1;
        unsigned l0 = 0xFFFFu, l1 = 0xFFFFu;
        int i0 = threadIdx.x, i1 = threadIdx.x + BPT;
        if (i0 < cnt) { r0 = vsrc[cb + i0]; l0 = lsrc[cb + i0]; atomicAdd(&hist[l0], 1u); }
        if (i1 < cnt) { r1 = vsrc[cb + i1]; l1 = lsrc[cb + i1]; atomicAdd(&hist[l1], 1u); }
        __syncthreads();

        scan_bins<NPC>(hist, incl, starts, cur, wsum, woff);

        if (l0 != 0xFFFFu) { unsigned p = atomicAdd(&cur[l0], 1u); vstage[p] = r0; }
        if (l1 != 0xFFFFu) { unsigned p = atomicAdd(&cur[l1], 1u); vstage[p] = r1; }
        __syncthreads();

        if (threadIdx.x < NPC) {
            unsigned s = starts[threadIdx.x];
            unsigned e = (threadIdx.x == NPC - 1) ? (unsigned)cnt
                                                  : starts[threadIdx.x + 1];
            if (e > s) {
                float f0 = 0.f, f1 = 0.f, f2 = 0.f, f3 = 0.f;
                float f4 = 0.f, f5 = 0.f, f6 = 0.f, f7 = 0.f;
                for (unsigned j = s; j < e; ++j) {
                    uint4 v = vstage[j];
                    f0 += bf_lo(v.x); f1 += bf_hi(v.x);
                    f2 += bf_lo(v.y); f3 += bf_hi(v.y);
                    f4 += bf_lo(v.z); f5 += bf_hi(v.z);
                    f6 += bf_lo(v.w); f7 += bf_hi(v.w);
                }
                float* a = acc + threadIdx.x * 9;
                a[0] += f0; a[1] += f1; a[2] += f2; a[3] += f3;
                a[4] += f4; a[5] += f5; a[6] += f6; a[7] += f7;
                a[8] += (float)(e - s);
            }
        }
        __syncthreads();
    }

    if (threadIdx.x < NPC) {
        int node = (c << NPCSH) + threadIdx.x;
        if (node < n_nodes) {
            const float* a = acc + threadIdx.x * 9;
            float inv = 1.0f / fmaxf(a[8], 1.0f);
            float4 o0 = { a[0] * inv, a[1] * inv, a[2] * inv, a[3] * inv };
            float4 o1 = { a[4] * inv, a[5] * inv, a[6] * inv, a[7] * inv };
            out_node4[(size_t)node * 2 + 0] = o0;
            out_node4[(size_t)node * 2 + 1] = o1;
        }
    }
}

// =============== pairs path (round-5, proven fallback) ===============

__global__ __launch_bounds__(APT) void edge_phase_kernel(
    const float4* __restrict__ x4,
    const int* __restrict__ src_idx,
    const int* __restrict__ dst_idx,
    const float4* __restrict__ ea4,
    float4* __restrict__ out_edge4,
    unsigned* __restrict__ cursors,
    unsigned* __restrict__ pairs,
    int n_edges, int nb, int cap)
{
    __shared__ unsigned hist[NBMAX];
    __shared__ unsigned base[NBMAX];
    __shared__ unsigned cur[NBMAX];
    __shared__ unsigned tld[EPBF];

    for (int b = threadIdx.x; b < nb; b += APT) { hist[b] = 0u; cur[b] = 0u; }
    __syncthreads();

    const int start = blockIdx.x * EPBF;
    int lim = n_edges - start;
    if (lim > EPBF) lim = EPBF;
    if (lim < 0) lim = 0;

    for (int i = threadIdx.x; i < lim; i += APT) {
        int e = start + i;
        int s = src_idx[e];
        int t = dst_idx[e];
        tld[i] = (unsigned)t;
        float4 xs0 = x4[(size_t)s * 2 + 0];
        float4 xs1 = x4[(size_t)s * 2 + 1];
        float4 xd0 = x4[(size_t)t * 2 + 0];
        float4 xd1 = x4[(size_t)t * 2 + 1];
        float4 a0  = ea4[(size_t)e * 2 + 0];
        float4 a1  = ea4[(size_t)e * 2 + 1];
        float4 d0, d1;
        d0.x = (xd0.x - xs0.x) / a0.x;
        d0.y = (xd0.y - xs0.y) / a0.y;
        d0.z = (xd0.z - xs0.z) / a0.z;
        d0.w = (xd0.w - xs0.w) / a0.w;
        d1.x = (xd1.x - xs1.x) / a1.x;
        d1.y = (xd1.y - xs1.y) / a1.y;
        d1.z = (xd1.z - xs1.z) / a1.z;
        d1.w = (xd1.w - xs1.w) / a1.w;
        out_edge4[(size_t)e * 2 + 0] = d0;
        out_edge4[(size_t)e * 2 + 1] = d1;
        atomicAdd(&hist[t >> BSH], 1u);
    }
    __syncthreads();

    for (int b = threadIdx.x; b < nb; b += APT)
        base[b] = hist[b] ? atomicAdd(&cursors[b], hist[b]) : 0u;
    __syncthreads();

    for (int i = threadIdx.x; i < lim; i += APT) {
        int e = start + i;
        unsigned t = tld[i];
        unsigned b = t >> BSH;
        unsigned p = base[b] + atomicAdd(&cur[b], 1u);
        if (p < (unsigned)cap)
            pairs[(size_t)b * cap + p] = ((unsigned)e << BSH) | (t & BMASK);
    }
}

__device__ __forceinline__ void acc9(float* __restrict__ acc, unsigned loc,
                                     float4 d0, float4 d1) {
    float* a = acc + loc * 9;
    atomicAdd(a + 0, d0.x);
    atomicAdd(a + 1, d0.y);
    atomicAdd(a + 2, d0.z);
    atomicAdd(a + 3, d0.w);
    atomicAdd(a + 4, d1.x);
    atomicAdd(a + 5, d1.y);
    atomicAdd(a + 6, d1.z);
    atomicAdd(a + 7, d1.w);
    atomicAdd(a + 8, 1.0f);
}

__global__ __launch_bounds__(RPT5) void bucket_reduce_kernel(
    const unsigned* __restrict__ cursors,
    const unsigned* __restrict__ pairs,
    const float4* __restrict__ edge4,
    float4* __restrict__ out_node4,
    int n_nodes, int cap)
{
    __shared__ float acc[64 * 9];
    for (int j = threadIdx.x; j < 64 * 9; j += RPT5) acc[j] = 0.0f;
    __syncthreads();

    const int b = blockIdx.x;
    int count = (int)cursors[b];
    if (count > cap) count = cap;
    const unsigned* pb = pairs + (size_t)b * cap;

    for (int i = threadIdx.x; i < count; i += RPT5) {
        unsigned pr = pb[i];
        float4 d0 = edge4[(size_t)(pr >> BSH) * 2 + 0];
        float4 d1 = edge4[(size_t)(pr >> BSH) * 2 + 1];
        acc9(acc, pr & BMASK, d0, d1);
    }
    __syncthreads();

    if (threadIdx.x < 128) {
        int loc  = threadIdx.x >> 1;
        int half = threadIdx.x & 1;
        int node = (b << BSH) + loc;
        if (node < n_nodes) {
            const float* a = acc + loc * 9;
            float inv = 1.0f / fmaxf(a[8], 1.0f);
            float4 o = { a[half * 4 + 0] * inv, a[half * 4 + 1] * inv,
                         a[half * 4 + 2] * inv, a[half * 4 + 3] * inv };
            out_node4[(size_t)node * 2 + half] = o;
        }
    }
}

// =============== atomic fallback (round-2, proven) ===============

__global__ void fb_zero_kernel(float* __restrict__ node_out, int n_node_f,
                               float* __restrict__ counts, int n_counts) {
    int stride = gridDim.x * blockDim.x;
    int tid = blockIdx.x * blockDim.x + threadIdx.x;
    for (int i = tid; i < n_node_f; i += stride) node_out[i] = 0.0f;
    for (int i = tid; i < n_counts; i += stride) counts[i] = 0.0f;
}

__global__ void fb_edge_kernel(const float4* __restrict__ x4,
                               const int* __restrict__ src_idx,
                               const int* __restrict__ dst_idx,
                               const float4* __restrict__ ea4,
                               float4* __restrict__ out_edge4,
                               float* __restrict__ node_sums,
                               float* __restrict__ counts,
                               int n_edges) {
    int e = blockIdx.x * blockDim.x + threadIdx.x;
    if (e >= n_edges) return;
    int s = src_idx[e];
    int t = dst_idx[e];
    float4 xs0 = x4[(size_t)s * 2 + 0];
    float4 xs1 = x4[(size_t)s * 2 + 1];
    float4 xd0 = x4[(size_t)t * 2 + 0];
    float4 xd1 = x4[(size_t)t * 2 + 1];
    float4 a0  = ea4[(size_t)e * 2 + 0];
    float4 a1  = ea4[(size_t)e * 2 + 1];
    float4 d0, d1;
    d0.x = (xd0.x - xs0.x) / a0.x;
    d0.y = (xd0.y - xs0.y) / a0.y;
    d0.z = (xd0.z - xs0.z) / a0.z;
    d0.w = (xd0.w - xs0.w) / a0.w;
    d1.x = (xd1.x - xs1.x) / a1.x;
    d1.y = (xd1.y - xs1.y) / a1.y;
    d1.z = (xd1.z - xs1.z) / a1.z;
    d1.w = (xd1.w - xs1.w) / a1.w;
    out_edge4[(size_t)e * 2 + 0] = d0;
    out_edge4[(size_t)e * 2 + 1] = d1;
    float* sp = node_sums + (size_t)t * D;
    atomicAdd(sp + 0, d0.x);
    atomicAdd(sp + 1, d0.y);
    atomicAdd(sp + 2, d0.z);
    atomicAdd(sp + 3, d0.w);
    atomicAdd(sp + 4, d1.x);
    atomicAdd(sp + 5, d1.y);
    atomicAdd(sp + 6, d1.z);
    atomicAdd(sp + 7, d1.w);
    atomicAdd(counts + t, 1.0f);
}

__global__ void fb_node_kernel(float4* __restrict__ node4,
                               const float* __restrict__ counts,
                               int n_nodes) {
    int n = blockIdx.x * blockDim.x + threadIdx.x;
    if (n >= n_nodes) return;
    float inv = 1.0f / fmaxf(counts[n], 1.0f);
    float4 s0 = node4[(size_t)n * 2 + 0];
    float4 s1 = node4[(size_t)n * 2 + 1];
    s0.x *= inv; s0.y *= inv; s0.z *= inv; s0.w *= inv;
    s1.x *= inv; s1.y *= inv; s1.z *= inv; s1.w *= inv;
    node4[(size_t)n * 2 + 0] = s0;
    node4[(size_t)n * 2 + 1] = s1;
}

// ---------------- launch ----------------

extern "C" void kernel_launch(void* const* d_in, const int* in_sizes, int n_in,
                              void* d_out, int out_size, void* d_ws, size_t ws_size,
                              hipStream_t stream) {
    const float* x  = (const float*)d_in[0];
    const int*   ei = (const int*)d_in[1];
    const float* ea = (const float*)d_in[2];

    const int n_nodes = in_sizes[0] / D;
    const int n_edges = in_sizes[2] / D;

    const int* src_idx = ei;
    const int* dst_idx = ei + n_edges;

    float* out_node = (float*)d_out;
    float* out_edge = out_node + (size_t)n_nodes * D;

    // --- split coarse-sort fast path ---
    {
        const int nc = (n_nodes + NPC - 1) >> NPCSH;
        long long meanc = nc > 0 ? (long long)n_edges / nc : 0;
        int capc = (int)(meanc + meanc / 8 + 1024);
        size_t gcur_b = ((size_t)nc * 4 + 255) & ~(size_t)255;
        size_t vals_b = (size_t)nc * capc * 16;
        size_t locs_b = (size_t)nc * capc * 2;
        size_t need = gcur_b + vals_b + locs_b + 256;

        if (nc >= 1 && nc <= NCMAX && ws_size >= need) {
            unsigned*       gcur = (unsigned*)d_ws;
            uint4*          vals = (uint4*)((char*)d_ws + gcur_b);
            unsigned short* locs = (unsigned short*)((char*)d_ws + gcur_b + vals_b);

            zero_cursors_kernel<<<(nc + 255) / 256, 256, 0, stream>>>(gcur, nc);
            // 512 edges per 256-thread block (2 lanes/edge × 4 unroll)
            int blocksC = (n_edges + 128 * UE - 1) / (128 * UE);
            edge_compute4_kernel<<<blocksC, 256, 0, stream>>>(
                (const float4*)x, src_idx, dst_idx, (const float4*)ea,
                (float4*)out_edge, n_edges);
            int blocksS = (n_edges + EPB - 1) / EPB;
            edge_sortk_kernel<<<blocksS, APT, 0, stream>>>(
                dst_idx, (const float4*)out_edge, gcur, vals, locs,
                n_edges, nc, capc);
            coarse_reduce_kernel<<<nc, BPT, 0, stream>>>(
                gcur, vals, locs, (float4*)out_node, n_nodes, capc);
            return;
        }
    }

    // --- pairs path (round-5) ---
    {
        const int nb = (n_nodes + BMASK) >> BSH;
        int cap = (int)(((long long)n_edges / (nb > 0 ? nb : 1) + 256) * 3 / 2);
        cap = (cap + 3) & ~3;
        size_t cursors_bytes = ((size_t)nb * 4 + 255) & ~(size_t)255;
        size_t need = cursors_bytes + (size_t)nb * cap * 4;
        if (nb <= NBMAX && ws_size >= need) {
            unsigned* cursors = (unsigned*)d_ws;
            unsigned* pairs   = (unsigned*)((char*)d_ws + cursors_bytes);

            int blocksA = (n_edges + EPBF - 1) / EPBF;
            zero_cursors_kernel<<<(nb + 255) / 256, 256, 0, stream>>>(cursors, nb);
            edge_phase_kernel<<<blocksA, APT, 0, stream>>>(
                (const float4*)x, src_idx, dst_idx, (const float4*)ea,
                (float4*)out_edge, cursors, pairs, n_edges, nb, cap);
            bucket_reduce_kernel<<<nb, RPT5, 0, stream>>>(
                cursors, pairs, (const float4*)out_edge, (float4*)out_node,
                n_nodes, cap);
            return;
        }
    }

    // --- atomic fallback ---
    {
        float* counts = (float*)d_ws;
        int n = n_nodes * D;
        int blocks = (n + 255) / 256;
        if (blocks > 2048) blocks = 2048;
        fb_zero_kernel<<<blocks, 256, 0, stream>>>(out_node, n, counts, n_nodes);
        fb_edge_kernel<<<(n_edges + 255) / 256, 256, 0, stream>>>(
            (const float4*)x, src_idx, dst_idx, (const float4*)ea,
            (float4*)out_edge, out_node, counts, n_edges);
        fb_node_kernel<<<(n_nodes + 255) / 256, 256, 0, stream>>>(
            (float4*)out_node, counts, n_nodes);
    }
}

// Round 14
// 163.108 us; speedup vs baseline: 1.0163x; 1.0163x over previous
//
#include <hip/hip_runtime.h>
#include <math.h>

#define D 8
// ---- coarse-sort fast path ----
#define NPC 512            // nodes per coarse bucket (power of 2)
#define NPCSH 9
#define NCMAX 512          // max coarse buckets on fast path
#define EPB 3072           // edges per sort-kernel block
#define APT 1024           // sort-kernel threads
#define BCH 1536           // phase-B chunk (records)
#define BPT 1024           // phase-B threads
#define UE 4               // K1: edges-unroll per thread-pair
// ---- pairs fallback path ----
#define BSH 6
#define BMASK 63
#define NBMAX 1600
#define EPBF 6250          // fallback pairs-path edges per block
#define RPT5 512

typedef __attribute__((ext_vector_type(4))) float f4v;

// ---- bf16 helpers ----
__device__ __forceinline__ unsigned pk_bf16(float a, float b) {
    unsigned ua = __float_as_uint(a), ub = __float_as_uint(b);
    ua = (ua + 0x7FFFu + ((ua >> 16) & 1u)) >> 16;   // RTNE
    ub = (ub + 0x7FFFu + ((ub >> 16) & 1u)) >> 16;
    return ua | (ub << 16);
}
__device__ __forceinline__ float bf_lo(unsigned u) { return __uint_as_float(u << 16); }
__device__ __forceinline__ float bf_hi(unsigned u) { return __uint_as_float(u & 0xFFFF0000u); }

__global__ void zero_cursors_kernel(unsigned* __restrict__ cur, int n) {
    int i = blockIdx.x * blockDim.x + threadIdx.x;
    if (i < n) cur[i] = 0u;
}

// block-wide exclusive scan over NB bins (NB multiple of 64, <= blockDim)
template<int NB>
__device__ __forceinline__ void scan_bins(unsigned* hist, unsigned* incl,
                                          unsigned* starts, unsigned* cur,
                                          unsigned* wsum, unsigned* woff) {
    int tid = threadIdx.x;
    if (tid < NB) {
        int l = tid & 63;
        unsigned v = hist[tid], s = v;
#pragma unroll
        for (int dd = 1; dd < 64; dd <<= 1) {
            unsigned tt = __shfl_up(s, dd, 64);
            if (l >= dd) s += tt;
        }
        incl[tid] = s;
        if (l == 63) wsum[tid >> 6] = s;
    }
    __syncthreads();
    if (tid == 0) {
        unsigned o = 0;
#pragma unroll
        for (int w = 0; w < NB / 64; ++w) { woff[w] = o; o += wsum[w]; }
    }
    __syncthreads();
    if (tid < NB) {
        unsigned st = incl[tid] - hist[tid] + woff[tid >> 6];
        starts[tid] = st;
        cur[tid] = st;
    }
    __syncthreads();
}

// =============== K1: gather/compute, 2 lanes/edge, 4-edge unroll ===============
// NT loads for ea (single-use stream, keep out of L2 so x stays cached).
// NORMAL stores for out_edge — K2 re-reads it immediately; NT store here
// cost +17 µs in K2 (round-13 lesson).

__global__ __launch_bounds__(256, 6) void edge_compute4_kernel(
    const float4* __restrict__ x4,
    const int* __restrict__ src_idx,
    const int* __restrict__ dst_idx,
    const float4* __restrict__ ea4,
    float4* __restrict__ out_edge4,
    int n_edges)
{
    const int h    = threadIdx.x & 1;          // low/high float4 half
    const int eo   = threadIdx.x >> 1;         // 0..127
    const int base = blockIdx.x * (128 * UE);

    int e[UE], s[UE], t[UE];
    bool v[UE];
#pragma unroll
    for (int u = 0; u < UE; ++u) {
        e[u] = base + u * 128 + eo;
        v[u] = e[u] < n_edges;
        s[u] = v[u] ? src_idx[e[u]] : 0;
        t[u] = v[u] ? dst_idx[e[u]] : 0;
    }

    // batch all gathers + streaming loads before any compute (max MLP)
    float4 xs[UE], xd[UE], a[UE];
#pragma unroll
    for (int u = 0; u < UE; ++u) {
        if (v[u]) {
            xs[u] = x4[(size_t)s[u] * 2 + h];   // adjacent lanes merge to 1 line
            xd[u] = x4[(size_t)t[u] * 2 + h];
        }
    }
#pragma unroll
    for (int u = 0; u < UE; ++u) {
        if (v[u]) {
            f4v av = __builtin_nontemporal_load(
                (const f4v*)&ea4[(size_t)e[u] * 2 + h]);
            a[u] = *(float4*)&av;
        }
    }

#pragma unroll
    for (int u = 0; u < UE; ++u) {
        if (v[u]) {
            float4 d;
            d.x = (xd[u].x - xs[u].x) / a[u].x;
            d.y = (xd[u].y - xs[u].y) / a[u].y;
            d.z = (xd[u].z - xs[u].z) / a[u].z;
            d.w = (xd[u].w - xs[u].w) / a[u].w;
            out_edge4[(size_t)e[u] * 2 + h] = d;   // cached store: K2 re-reads
        }
    }
}

// =============== K2: streaming counting-sort into coarse regions ===============

__global__ __launch_bounds__(APT) void edge_sortk_kernel(
    const int* __restrict__ dst_idx,
    const float4* __restrict__ edge4,
    unsigned* __restrict__ gcur,          // [nc]
    uint4* __restrict__ vals,             // [nc*cap]
    unsigned short* __restrict__ locs,    // [nc*cap]
    int n_edges, int nc, int cap)
{
    __shared__ uint4 pay[EPB];            // 49152 B — bf16 payload (sorted order)
    __shared__ unsigned meta[EPB];        // 12288 B — node id (sorted order)
    __shared__ unsigned hist[NCMAX];
    __shared__ unsigned incl[NCMAX];
    __shared__ unsigned starts[NCMAX];
    __shared__ unsigned cur[NCMAX];
    __shared__ unsigned base[NCMAX];
    __shared__ unsigned wsum[NCMAX / 64], woff[NCMAX / 64];

    for (int c = threadIdx.x; c < NCMAX; c += APT) hist[c] = 0u;
    __syncthreads();

    const int start = blockIdx.x * EPB;
    int lim = n_edges - start;
    if (lim > EPB) lim = EPB;
    if (lim < 0) lim = 0;

    // pass A: histogram of coarse buckets (dst streaming read)
    for (int i = threadIdx.x; i < lim; i += APT) {
        unsigned t = (unsigned)dst_idx[start + i];
        atomicAdd(&hist[t >> NPCSH], 1u);
    }
    __syncthreads();

    scan_bins<NCMAX>(hist, incl, starts, cur, wsum, woff);

    // reserve global run space
    if (threadIdx.x < (unsigned)nc)
        base[threadIdx.x] = hist[threadIdx.x]
            ? atomicAdd(&gcur[threadIdx.x], hist[threadIdx.x]) : 0u;

    // pass B: stream edge_deriv (coalesced), convert bf16, direct-scatter into
    // sorted LDS position
    for (int i = threadIdx.x; i < lim; i += APT) {
        int e = start + i;
        unsigned t = (unsigned)dst_idx[e];      // L2-hot re-read
        float4 d0 = edge4[(size_t)e * 2 + 0];
        float4 d1 = edge4[(size_t)e * 2 + 1];
        unsigned p = atomicAdd(&cur[t >> NPCSH], 1u);
        uint4 v = { pk_bf16(d0.x, d0.y), pk_bf16(d0.z, d0.w),
                    pk_bf16(d1.x, d1.y), pk_bf16(d1.z, d1.w) };
        pay[p] = v;
        meta[p] = t;
    }
    __syncthreads();

    // pass C: coalesced LDS read -> coalesced global run write
    for (int p = threadIdx.x; p < lim; p += APT) {
        unsigned t = meta[p];
        unsigned c = t >> NPCSH;
        unsigned addr = base[c] + ((unsigned)p - starts[c]);
        if (addr < (unsigned)cap) {
            size_t gi = (size_t)c * cap + addr;
            vals[gi] = pay[p];
            locs[gi] = (unsigned short)(t & (NPC - 1));
        }
    }
}

// =============== K3: coarse reduce (round-8, proven ~7 µs) ===============

__global__ __launch_bounds__(BPT) void coarse_reduce_kernel(
    const unsigned* __restrict__ gcur,
    const uint4* __restrict__ vals,
    const unsigned short* __restrict__ locs,
    float4* __restrict__ out_node4,
    int n_nodes, int cap)
{
    __shared__ float acc[NPC * 9];        // 18432 B
    __shared__ uint4 vstage[BCH];         // 24576 B
    __shared__ unsigned hist[NPC];
    __shared__ unsigned incl[NPC];
    __shared__ unsigned starts[NPC];
    __shared__ unsigned cur[NPC];
    __shared__ unsigned wsum[NPC / 64], woff[NPC / 64];

    const int c = blockIdx.x;
    int count = (int)gcur[c];
    if (count > cap) count = cap;
    const uint4* vsrc = vals + (size_t)c * cap;
    const unsigned short* lsrc = locs + (size_t)c * cap;

    for (int j = threadIdx.x; j < NPC * 9; j += BPT) acc[j] = 0.0f;
    __syncthreads();

    for (int cb = 0; cb < count; cb += BCH) {
        int cnt = count - cb;
        if (cnt > BCH) cnt = BCH;

        for (int j = threadIdx.x; j < NPC; j += BPT) hist[j] = 0u;
        __syncthreads();

        uint4 r0, r1;
        unsigned l0 = 0xFFFFu, l1 = 0xFFFFu;
        int i0 = threadIdx.x, i1 = threadIdx.x + BPT;
        if (i0 < cnt) { r0 = vsrc[cb + i0]; l0 = lsrc[cb + i0]; atomicAdd(&hist[l0], 1u); }
        if (i1 < cnt) { r1 = vsrc[cb + i1]; l1 = lsrc[cb + i1]; atomicAdd(&hist[l1], 1u); }
        __syncthreads();

        scan_bins<NPC>(hist, incl, starts, cur, wsum, woff);

        if (l0 != 0xFFFFu) { unsigned p = atomicAdd(&cur[l0], 1u); vstage[p] = r0; }
        if (l1 != 0xFFFFu) { unsigned p = atomicAdd(&cur[l1], 1u); vstage[p] = r1; }
        __syncthreads();

        if (threadIdx.x < NPC) {
            unsigned s = starts[threadIdx.x];
            unsigned e = (threadIdx.x == NPC - 1) ? (unsigned)cnt
                                                  : starts[threadIdx.x + 1];
            if (e > s) {
                float f0 = 0.f, f1 = 0.f, f2 = 0.f, f3 = 0.f;
                float f4 = 0.f, f5 = 0.f, f6 = 0.f, f7 = 0.f;
                for (unsigned j = s; j < e; ++j) {
                    uint4 v = vstage[j];
                    f0 += bf_lo(v.x); f1 += bf_hi(v.x);
                    f2 += bf_lo(v.y); f3 += bf_hi(v.y);
                    f4 += bf_lo(v.z); f5 += bf_hi(v.z);
                    f6 += bf_lo(v.w); f7 += bf_hi(v.w);
                }
                float* a = acc + threadIdx.x * 9;
                a[0] += f0; a[1] += f1; a[2] += f2; a[3] += f3;
                a[4] += f4; a[5] += f5; a[6] += f6; a[7] += f7;
                a[8] += (float)(e - s);
            }
        }
        __syncthreads();
    }

    if (threadIdx.x < NPC) {
        int node = (c << NPCSH) + threadIdx.x;
        if (node < n_nodes) {
            const float* a = acc + threadIdx.x * 9;
            float inv = 1.0f / fmaxf(a[8], 1.0f);
            float4 o0 = { a[0] * inv, a[1] * inv, a[2] * inv, a[3] * inv };
            float4 o1 = { a[4] * inv, a[5] * inv, a[6] * inv, a[7] * inv };
            out_node4[(size_t)node * 2 + 0] = o0;
            out_node4[(size_t)node * 2 + 1] = o1;
        }
    }
}

// =============== pairs path (round-5, proven fallback) ===============

__global__ __launch_bounds__(APT) void edge_phase_kernel(
    const float4* __restrict__ x4,
    const int* __restrict__ src_idx,
    const int* __restrict__ dst_idx,
    const float4* __restrict__ ea4,
    float4* __restrict__ out_edge4,
    unsigned* __restrict__ cursors,
    unsigned* __restrict__ pairs,
    int n_edges, int nb, int cap)
{
    __shared__ unsigned hist[NBMAX];
    __shared__ unsigned base[NBMAX];
    __shared__ unsigned cur[NBMAX];
    __shared__ unsigned tld[EPBF];

    for (int b = threadIdx.x; b < nb; b += APT) { hist[b] = 0u; cur[b] = 0u; }
    __syncthreads();

    const int start = blockIdx.x * EPBF;
    int lim = n_edges - start;
    if (lim > EPBF) lim = EPBF;
    if (lim < 0) lim = 0;

    for (int i = threadIdx.x; i < lim; i += APT) {
        int e = start + i;
        int s = src_idx[e];
        int t = dst_idx[e];
        tld[i] = (unsigned)t;
        float4 xs0 = x4[(size_t)s * 2 + 0];
        float4 xs1 = x4[(size_t)s * 2 + 1];
        float4 xd0 = x4[(size_t)t * 2 + 0];
        float4 xd1 = x4[(size_t)t * 2 + 1];
        float4 a0  = ea4[(size_t)e * 2 + 0];
        float4 a1  = ea4[(size_t)e * 2 + 1];
        float4 d0, d1;
        d0.x = (xd0.x - xs0.x) / a0.x;
        d0.y = (xd0.y - xs0.y) / a0.y;
        d0.z = (xd0.z - xs0.z) / a0.z;
        d0.w = (xd0.w - xs0.w) / a0.w;
        d1.x = (xd1.x - xs1.x) / a1.x;
        d1.y = (xd1.y - xs1.y) / a1.y;
        d1.z = (xd1.z - xs1.z) / a1.z;
        d1.w = (xd1.w - xs1.w) / a1.w;
        out_edge4[(size_t)e * 2 + 0] = d0;
        out_edge4[(size_t)e * 2 + 1] = d1;
        atomicAdd(&hist[t >> BSH], 1u);
    }
    __syncthreads();

    for (int b = threadIdx.x; b < nb; b += APT)
        base[b] = hist[b] ? atomicAdd(&cursors[b], hist[b]) : 0u;
    __syncthreads();

    for (int i = threadIdx.x; i < lim; i += APT) {
        int e = start + i;
        unsigned t = tld[i];
        unsigned b = t >> BSH;
        unsigned p = base[b] + atomicAdd(&cur[b], 1u);
        if (p < (unsigned)cap)
            pairs[(size_t)b * cap + p] = ((unsigned)e << BSH) | (t & BMASK);
    }
}

__device__ __forceinline__ void acc9(float* __restrict__ acc, unsigned loc,
                                     float4 d0, float4 d1) {
    float* a = acc + loc * 9;
    atomicAdd(a + 0, d0.x);
    atomicAdd(a + 1, d0.y);
    atomicAdd(a + 2, d0.z);
    atomicAdd(a + 3, d0.w);
    atomicAdd(a + 4, d1.x);
    atomicAdd(a + 5, d1.y);
    atomicAdd(a + 6, d1.z);
    atomicAdd(a + 7, d1.w);
    atomicAdd(a + 8, 1.0f);
}

__global__ __launch_bounds__(RPT5) void bucket_reduce_kernel(
    const unsigned* __restrict__ cursors,
    const unsigned* __restrict__ pairs,
    const float4* __restrict__ edge4,
    float4* __restrict__ out_node4,
    int n_nodes, int cap)
{
    __shared__ float acc[64 * 9];
    for (int j = threadIdx.x; j < 64 * 9; j += RPT5) acc[j] = 0.0f;
    __syncthreads();

    const int b = blockIdx.x;
    int count = (int)cursors[b];
    if (count > cap) count = cap;
    const unsigned* pb = pairs + (size_t)b * cap;

    for (int i = threadIdx.x; i < count; i += RPT5) {
        unsigned pr = pb[i];
        float4 d0 = edge4[(size_t)(pr >> BSH) * 2 + 0];
        float4 d1 = edge4[(size_t)(pr >> BSH) * 2 + 1];
        acc9(acc, pr & BMASK, d0, d1);
    }
    __syncthreads();

    if (threadIdx.x < 128) {
        int loc  = threadIdx.x >> 1;
        int half = threadIdx.x & 1;
        int node = (b << BSH) + loc;
        if (node < n_nodes) {
            const float* a = acc + loc * 9;
            float inv = 1.0f / fmaxf(a[8], 1.0f);
            float4 o = { a[half * 4 + 0] * inv, a[half * 4 + 1] * inv,
                         a[half * 4 + 2] * inv, a[half * 4 + 3] * inv };
            out_node4[(size_t)node * 2 + half] = o;
        }
    }
}

// =============== atomic fallback (round-2, proven) ===============

__global__ void fb_zero_kernel(float* __restrict__ node_out, int n_node_f,
                               float* __restrict__ counts, int n_counts) {
    int stride = gridDim.x * blockDim.x;
    int tid = blockIdx.x * blockDim.x + threadIdx.x;
    for (int i = tid; i < n_node_f; i += stride) node_out[i] = 0.0f;
    for (int i = tid; i < n_counts; i += stride) counts[i] = 0.0f;
}

__global__ void fb_edge_kernel(const float4* __restrict__ x4,
                               const int* __restrict__ src_idx,
                               const int* __restrict__ dst_idx,
                               const float4* __restrict__ ea4,
                               float4* __restrict__ out_edge4,
                               float* __restrict__ node_sums,
                               float* __restrict__ counts,
                               int n_edges) {
    int e = blockIdx.x * blockDim.x + threadIdx.x;
    if (e >= n_edges) return;
    int s = src_idx[e];
    int t = dst_idx[e];
    float4 xs0 = x4[(size_t)s * 2 + 0];
    float4 xs1 = x4[(size_t)s * 2 + 1];
    float4 xd0 = x4[(size_t)t * 2 + 0];
    float4 xd1 = x4[(size_t)t * 2 + 1];
    float4 a0  = ea4[(size_t)e * 2 + 0];
    float4 a1  = ea4[(size_t)e * 2 + 1];
    float4 d0, d1;
    d0.x = (xd0.x - xs0.x) / a0.x;
    d0.y = (xd0.y - xs0.y) / a0.y;
    d0.z = (xd0.z - xs0.z) / a0.z;
    d0.w = (xd0.w - xs0.w) / a0.w;
    d1.x = (xd1.x - xs1.x) / a1.x;
    d1.y = (xd1.y - xs1.y) / a1.y;
    d1.z = (xd1.z - xs1.z) / a1.z;
    d1.w = (xd1.w - xs1.w) / a1.w;
    out_edge4[(size_t)e * 2 + 0] = d0;
    out_edge4[(size_t)e * 2 + 1] = d1;
    float* sp = node_sums + (size_t)t * D;
    atomicAdd(sp + 0, d0.x);
    atomicAdd(sp + 1, d0.y);
    atomicAdd(sp + 2, d0.z);
    atomicAdd(sp + 3, d0.w);
    atomicAdd(sp + 4, d1.x);
    atomicAdd(sp + 5, d1.y);
    atomicAdd(sp + 6, d1.z);
    atomicAdd(sp + 7, d1.w);
    atomicAdd(counts + t, 1.0f);
}

__global__ void fb_node_kernel(float4* __restrict__ node4,
                               const float* __restrict__ counts,
                               int n_nodes) {
    int n = blockIdx.x * blockDim.x + threadIdx.x;
    if (n >= n_nodes) return;
    float inv = 1.0f / fmaxf(counts[n], 1.0f);
    float4 s0 = node4[(size_t)n * 2 + 0];
    float4 s1 = node4[(size_t)n * 2 + 1];
    s0.x *= inv; s0.y *= inv; s0.z *= inv; s0.w *= inv;
    s1.x *= inv; s1.y *= inv; s1.z *= inv; s1.w *= inv;
    node4[(size_t)n * 2 + 0] = s0;
    node4[(size_t)n * 2 + 1] = s1;
}

// ---------------- launch ----------------

extern "C" void kernel_launch(void* const* d_in, const int* in_sizes, int n_in,
                              void* d_out, int out_size, void* d_ws, size_t ws_size,
                              hipStream_t stream) {
    const float* x  = (const float*)d_in[0];
    const int*   ei = (const int*)d_in[1];
    const float* ea = (const float*)d_in[2];

    const int n_nodes = in_sizes[0] / D;
    const int n_edges = in_sizes[2] / D;

    const int* src_idx = ei;
    const int* dst_idx = ei + n_edges;

    float* out_node = (float*)d_out;
    float* out_edge = out_node + (size_t)n_nodes * D;

    // --- split coarse-sort fast path ---
    {
        const int nc = (n_nodes + NPC - 1) >> NPCSH;
        long long meanc = nc > 0 ? (long long)n_edges / nc : 0;
        int capc = (int)(meanc + meanc / 8 + 1024);
        size_t gcur_b = ((size_t)nc * 4 + 255) & ~(size_t)255;
        size_t vals_b = (size_t)nc * capc * 16;
        size_t locs_b = (size_t)nc * capc * 2;
        size_t need = gcur_b + vals_b + locs_b + 256;

        if (nc >= 1 && nc <= NCMAX && ws_size >= need) {
            unsigned*       gcur = (unsigned*)d_ws;
            uint4*          vals = (uint4*)((char*)d_ws + gcur_b);
            unsigned short* locs = (unsigned short*)((char*)d_ws + gcur_b + vals_b);

            zero_cursors_kernel<<<(nc + 255) / 256, 256, 0, stream>>>(gcur, nc);
            // 512 edges per 256-thread block (2 lanes/edge × 4 unroll)
            int blocksC = (n_edges + 128 * UE - 1) / (128 * UE);
            edge_compute4_kernel<<<blocksC, 256, 0, stream>>>(
                (const float4*)x, src_idx, dst_idx, (const float4*)ea,
                (float4*)out_edge, n_edges);
            int blocksS = (n_edges + EPB - 1) / EPB;
            edge_sortk_kernel<<<blocksS, APT, 0, stream>>>(
                dst_idx, (const float4*)out_edge, gcur, vals, locs,
                n_edges, nc, capc);
            coarse_reduce_kernel<<<nc, BPT, 0, stream>>>(
                gcur, vals, locs, (float4*)out_node, n_nodes, capc);
            return;
        }
    }

    // --- pairs path (round-5) ---
    {
        const int nb = (n_nodes + BMASK) >> BSH;
        int cap = (int)(((long long)n_edges / (nb > 0 ? nb : 1) + 256) * 3 / 2);
        cap = (cap + 3) & ~3;
        size_t cursors_bytes = ((size_t)nb * 4 + 255) & ~(size_t)255;
        size_t need = cursors_bytes + (size_t)nb * cap * 4;
        if (nb <= NBMAX && ws_size >= need) {
            unsigned* cursors = (unsigned*)d_ws;
            unsigned* pairs   = (unsigned*)((char*)d_ws + cursors_bytes);

            int blocksA = (n_edges + EPBF - 1) / EPBF;
            zero_cursors_kernel<<<(nb + 255) / 256, 256, 0, stream>>>(cursors, nb);
            edge_phase_kernel<<<blocksA, APT, 0, stream>>>(
                (const float4*)x, src_idx, dst_idx, (const float4*)ea,
                (float4*)out_edge, cursors, pairs, n_edges, nb, cap);
            bucket_reduce_kernel<<<nb, RPT5, 0, stream>>>(
                cursors, pairs, (const float4*)out_edge, (float4*)out_node,
                n_nodes, cap);
            return;
        }
    }

    // --- atomic fallback ---
    {
        float* counts = (float*)d_ws;
        int n = n_nodes * D;
        int blocks = (n + 255) / 256;
        if (blocks > 2048) blocks = 2048;
        fb_zero_kernel<<<blocks, 256, 0, stream>>>(out_node, n, counts, n_nodes);
        fb_edge_kernel<<<(n_edges + 255) / 256, 256, 0, stream>>>(
            (const float4*)x, src_idx, dst_idx, (const float4*)ea,
            (float4*)out_edge, out_node, counts, n_edges);
        fb_node_kernel<<<(n_nodes + 255) / 256, 256, 0, stream>>>(
            (float4*)out_node, counts, n_nodes);
    }
}